// Round 8
// baseline (425.327 us; speedup 1.0000x reference)
//
#include <hip/hip_runtime.h>
#include <hip/hip_bf16.h>

// NT-Xent (CLIP) loss, N=16384 D=256 fp32 in, 3 fp32 out.
// loss_vu = mean_i( log(sum_j exp(sim_ij)) - sim_ii ), sim = (v̂·û^T)/T
// Logits bounded by 1/T=14.29 -> no max subtraction needed.
//
// R2..R9 history: every variant of "stage A+B tiles to LDS between
// barriers" lands 224-280us. Accounting shows the DS pipe (frag reads
// 196k cyc/CU + staging writes ~100k) exceeds the MFMA pipe (159k) and
// is serialized by the barriers. R8 (direct frag loads from row-major
// global) died on uncoalesced gathers (FETCH 528MB).
//
// R10: FRAGMENT-MAJOR LAYOUT. K1 writes V',U' pre-packed in the exact
// MFMA fragment order: fragment f(g,ks) = 1KB holding rows [g*16,+16) x
// K [ks*32,+32); lane l's 16B at f + l*16 (l=quad*16+l15 holds
// row g*16+l15, k ks*32+quad*8..+8 -- the m89/m91-verified mapping).
// K2 then loads operands as single coalesced 1KB dwordx4 straight into
// MFMA registers: ZERO LDS, ZERO barriers. 512 blocks x 32-row strips;
// A-frags (64 VGPR) live across the kernel; B streamed over 64 j-tiles
// of 256 cols, ks-pipelined (2x16 VGPR banks). Per-jt epilogue: exp2 ->
// rowsum regs + colsum atomics (cols wave-exclusive). B re-read by all
// 512 blocks in the same j-order -> L2/L3-resident (U'=8MB).
// Gates: FETCH < ~100MB (else L2 failed), LDS=0, MfmaUtil up.

#define D_DIM 256

constexpr float INV_T = 1.0f / 0.07f;
constexpr float EXP2_SCALE = 1.44269504088896340736f / 0.07f;  // log2(e)/T

typedef __bf16 bf16x8 __attribute__((ext_vector_type(8)));
typedef float f32x4 __attribute__((ext_vector_type(4)));

// ---------------------------------------------------------------------------
// Kernel 1: L2-normalize fp32 -> bf16 in FRAGMENT-MAJOR layout.
// One wave = 2 rows: lane = sub(1)|pos(5); lane handles 8 elems
// [pos*8, +8) of row (blk*8 + wave*2 + sub). Norm-reduce over the
// 32-lane half (xor offsets 1..16 stay within the half).
// Fragment write: row r -> group g=r>>4, slot l15=r&15; chunk pos ->
// ks=pos>>2, quad=pos&3; elem offset (g*8+ks)*512 + (quad*16+l15)*8.
// V' pre-scaled by EXP2_SCALE; diag from unscaled v,u; zeroes row/colsum.
// ---------------------------------------------------------------------------
__global__ __launch_bounds__(256) void normalize_kernel(
    const float* __restrict__ img, const float* __restrict__ txt,
    __hip_bfloat16* __restrict__ Vf, __hip_bfloat16* __restrict__ Uf,
    float* __restrict__ diagarr, float* __restrict__ rowsum,
    float* __restrict__ colsum) {
  const int wave = threadIdx.x >> 6;
  const int lane = threadIdx.x & 63;
  const int sub = lane >> 5;   // 0/1: which of the wave's two rows
  const int pos = lane & 31;   // 8-elem chunk index within the row
  const int row = blockIdx.x * 8 + wave * 2 + sub;
  const size_t base = (size_t)row * D_DIM + pos * 8;

  const float4 i0 = *reinterpret_cast<const float4*>(&img[base]);
  const float4 i1 = *reinterpret_cast<const float4*>(&img[base + 4]);
  const float4 t0 = *reinterpret_cast<const float4*>(&txt[base]);
  const float4 t1 = *reinterpret_cast<const float4*>(&txt[base + 4]);

  float a = i0.x * i0.x + i0.y * i0.y + i0.z * i0.z + i0.w * i0.w +
            i1.x * i1.x + i1.y * i1.y + i1.z * i1.z + i1.w * i1.w;
  float b = t0.x * t0.x + t0.y * t0.y + t0.z * t0.z + t0.w * t0.w +
            t1.x * t1.x + t1.y * t1.y + t1.z * t1.z + t1.w * t1.w;
#pragma unroll
  for (int off = 1; off < 32; off <<= 1) {
    a += __shfl_xor(a, off, 64);
    b += __shfl_xor(b, off, 64);
  }
  const float si = 1.0f / fmaxf(sqrtf(a), 1e-8f);
  const float st = 1.0f / fmaxf(sqrtf(b), 1e-8f);

  const float vs = si * EXP2_SCALE;  // V pre-scaled by log2e/T
  __hip_bfloat16 vb8[8] = {
      __float2bfloat16(i0.x * vs), __float2bfloat16(i0.y * vs),
      __float2bfloat16(i0.z * vs), __float2bfloat16(i0.w * vs),
      __float2bfloat16(i1.x * vs), __float2bfloat16(i1.y * vs),
      __float2bfloat16(i1.z * vs), __float2bfloat16(i1.w * vs)};
  __hip_bfloat16 ub8[8] = {
      __float2bfloat16(t0.x * st), __float2bfloat16(t0.y * st),
      __float2bfloat16(t0.z * st), __float2bfloat16(t0.w * st),
      __float2bfloat16(t1.x * st), __float2bfloat16(t1.y * st),
      __float2bfloat16(t1.z * st), __float2bfloat16(t1.w * st)};

  const int g = row >> 4, l15r = row & 15;
  const int ks = pos >> 2, quad = pos & 3;
  const size_t foff = (size_t)(g * 8 + ks) * 512 + (quad * 16 + l15r) * 8;
  *reinterpret_cast<uint4*>(&Vf[foff]) = *reinterpret_cast<uint4*>(vb8);
  *reinterpret_cast<uint4*>(&Uf[foff]) = *reinterpret_cast<uint4*>(ub8);

  // diag v̂_i·û_i (unscaled)
  float d = (i0.x * si) * (t0.x * st) + (i0.y * si) * (t0.y * st) +
            (i0.z * si) * (t0.z * st) + (i0.w * si) * (t0.w * st) +
            (i1.x * si) * (t1.x * st) + (i1.y * si) * (t1.y * st) +
            (i1.z * si) * (t1.z * st) + (i1.w * si) * (t1.w * st);
#pragma unroll
  for (int off = 1; off < 32; off <<= 1) d += __shfl_xor(d, off, 64);
  if (pos == 0) diagarr[row] = d;

  if (threadIdx.x < 8) {
    rowsum[blockIdx.x * 8 + threadIdx.x] = 0.0f;
    colsum[blockIdx.x * 8 + threadIdx.x] = 0.0f;
  }
}

// ---------------------------------------------------------------------------
// Kernel 2: barrier-free, LDS-free streaming MFMA GEMM + online exp2 sums.
// Block = 32 rows (groups 2b, 2b+1) x all N cols. 4 waves; wave w covers
// cols [jt*256 + w*64, +64) each j-tile. A-frags held in regs (16x1KB
// coalesced loads, once). B-frags: 4x1KB coalesced loads per ks, pipelined
// one ks ahead; ks==7 prefetches next jt's ks0, whose latency hides under
// the per-jt exp2/colsum epilogue.
// acc layout (verified): row = mi*16 + quad*4 + r, col = ni*16 + l15.
// ---------------------------------------------------------------------------
__global__ __launch_bounds__(256) void gemm_lse_kernel(
    const __hip_bfloat16* __restrict__ Vf, const __hip_bfloat16* __restrict__ Uf,
    float* __restrict__ rowsum, float* __restrict__ colsum, int n) {
  const int tid = threadIdx.x;
  const int lane = tid & 63;
  const int w = tid >> 6;
  const int quad = lane >> 4;
  const int l15 = lane & 15;
  const int b = blockIdx.x;
  const int njt = n >> 8;  // j-tiles of 256 cols

  // A fragments for rows [b*32, +32): groups 2b, 2b+1 -- all K, once.
  bf16x8 a[2][8];
#pragma unroll
  for (int mi = 0; mi < 2; ++mi)
#pragma unroll
    for (int ks = 0; ks < 8; ++ks)
      a[mi][ks] = *reinterpret_cast<const bf16x8*>(
          Vf + (size_t)((2 * b + mi) * 8 + ks) * 512 + lane * 8);

  float rs[2][4] = {};  // rowsum partials (this thread's 4 cols per ni, all jt)

  // B base for this wave: group = jt*16 + w*4 + ni, frag (group*8 + ks).
  const __hip_bfloat16* Ub = Uf + (size_t)(w * 4) * 8 * 512 + lane * 8;

  bf16x8 bb[2][4];
#pragma unroll
  for (int ni = 0; ni < 4; ++ni)  // prologue: jt=0, ks=0
    bb[0][ni] = *reinterpret_cast<const bf16x8*>(Ub + (size_t)ni * 8 * 512);

  for (int jt = 0; jt < njt; ++jt) {
    const size_t jb = (size_t)jt * 16 * 8 * 512;
    const size_t jbn = (size_t)(jt < njt - 1 ? jt + 1 : jt) * 16 * 8 * 512;
    f32x4 acc[2][4] = {};

#pragma unroll
    for (int ks = 0; ks < 8; ++ks) {
      if (ks < 7) {
#pragma unroll
        for (int ni = 0; ni < 4; ++ni)
          bb[(ks + 1) & 1][ni] = *reinterpret_cast<const bf16x8*>(
              Ub + jb + (size_t)(ni * 8 + ks + 1) * 512);
      } else {
#pragma unroll
        for (int ni = 0; ni < 4; ++ni)  // next jt's ks0 -> bank 0
          bb[0][ni] = *reinterpret_cast<const bf16x8*>(
              Ub + jbn + (size_t)(ni * 8) * 512);
      }
#pragma unroll
      for (int mi = 0; mi < 2; ++mi)
#pragma unroll
        for (int ni = 0; ni < 4; ++ni)
          acc[mi][ni] = __builtin_amdgcn_mfma_f32_16x16x32_bf16(
              a[mi][ks], bb[ks & 1][ni], acc[mi][ni], 0, 0, 0);
    }

    // per-jt epilogue: exp2, rowsum regs, colsum atomics (cols wave-excl.)
    float cs0 = 0.f, cs1 = 0.f, cs2 = 0.f, cs3 = 0.f;
#pragma unroll
    for (int mi = 0; mi < 2; ++mi)
#pragma unroll
      for (int r = 0; r < 4; ++r) {
        const float e0 = __builtin_amdgcn_exp2f(acc[mi][0][r]);
        const float e1 = __builtin_amdgcn_exp2f(acc[mi][1][r]);
        const float e2 = __builtin_amdgcn_exp2f(acc[mi][2][r]);
        const float e3 = __builtin_amdgcn_exp2f(acc[mi][3][r]);
        rs[mi][r] += e0 + e1 + e2 + e3;
        cs0 += e0; cs1 += e1; cs2 += e2; cs3 += e3;
      }
    float csa[4] = {cs0, cs1, cs2, cs3};
#pragma unroll
    for (int ni = 0; ni < 4; ++ni) {
      float c = csa[ni];
      c += __shfl_xor(c, 16, 64);
      c += __shfl_xor(c, 32, 64);
      if (lane < 16)
        atomicAdd(&colsum[jt * 256 + w * 64 + ni * 16 + l15], c);
    }
  }

  // final rowsum: reduce over the 16 l15 lanes; rows block-exclusive
  // (4 waves contribute to the same 32 rows -> atomicAdd).
#pragma unroll
  for (int mi = 0; mi < 2; ++mi)
#pragma unroll
    for (int r = 0; r < 4; ++r) {
      float v = rs[mi][r];
      v += __shfl_xor(v, 1, 64);
      v += __shfl_xor(v, 2, 64);
      v += __shfl_xor(v, 4, 64);
      v += __shfl_xor(v, 8, 64);
      if (l15 == 0)
        atomicAdd(&rowsum[b * 32 + mi * 16 + quad * 4 + r], v);
    }
}

// ---------------------------------------------------------------------------
// Kernel 3: finalize — mean(log(rowsum)), mean(log(colsum)), mean(diag).
// ---------------------------------------------------------------------------
__global__ __launch_bounds__(1024) void finalize_kernel(
    const float* __restrict__ rowsum, const float* __restrict__ colsum,
    const float* __restrict__ diagarr, float* __restrict__ out, int n) {
  __shared__ float sh[48];
  float sr = 0.0f, sc = 0.0f, sd = 0.0f;
  for (int i = threadIdx.x; i < n; i += 1024) {
    sr += __logf(rowsum[i]);
    sc += __logf(colsum[i]);
    sd += diagarr[i];
  }
#pragma unroll
  for (int off = 1; off < 64; off <<= 1) {
    sr += __shfl_xor(sr, off, 64);
    sc += __shfl_xor(sc, off, 64);
    sd += __shfl_xor(sd, off, 64);
  }
  const int w = threadIdx.x >> 6, lane = threadIdx.x & 63;
  if (lane == 0) { sh[w] = sr; sh[16 + w] = sc; sh[32 + w] = sd; }
  __syncthreads();
  if (threadIdx.x == 0) {
    float tr = 0.0f, tc = 0.0f, td = 0.0f;
#pragma unroll
    for (int i = 0; i < 16; ++i) {
      tr += sh[i]; tc += sh[16 + i]; td += sh[32 + i];
    }
    const float invN = 1.0f / (float)n;
    const float dm = td * INV_T * invN;   // mean diag logit
    const float lvu = tr * invN - dm;
    const float luv = tc * invN - dm;
    out[0] = 0.5f * lvu + 0.5f * luv;  // WEIGHT = 0.5
    out[1] = lvu;
    out[2] = luv;
  }
}

extern "C" void kernel_launch(void* const* d_in, const int* in_sizes, int n_in,
                              void* d_out, int out_size, void* d_ws, size_t ws_size,
                              hipStream_t stream) {
  const float* img = (const float*)d_in[0];
  const float* txt = (const float*)d_in[1];
  float* out = (float*)d_out;
  const int N = in_sizes[0] / D_DIM;  // 16384

  char* ws = (char*)d_ws;
  __hip_bfloat16* Vf = (__hip_bfloat16*)ws;                             // 8MB
  __hip_bfloat16* Uf = (__hip_bfloat16*)(ws + (size_t)N * D_DIM * 2);   // 8MB
  float* rowsum = (float*)(ws + (size_t)N * D_DIM * 4);
  float* colsum = rowsum + N;
  float* diagarr = colsum + N;

  // rowsum/colsum zeroed inside normalize_kernel (ws poisoned pre-launch)
  normalize_kernel<<<N / 8, 256, 0, stream>>>(img, txt, Vf, Uf, diagarr,
                                              rowsum, colsum);

  gemm_lse_kernel<<<N / 32, 256, 0, stream>>>(Vf, Uf, rowsum, colsum, N);

  finalize_kernel<<<1, 1024, 0, stream>>>(rowsum, colsum, diagarr, out, N);
}

// Round 9
// 261.923 us; speedup vs baseline: 1.6239x; 1.6239x over previous
//
#include <hip/hip_runtime.h>
#include <hip/hip_bf16.h>

// NT-Xent (CLIP) loss, N=16384 D=256 fp32 in, 3 fp32 out.
// loss_vu = mean_i( log(sum_j exp(sim_ij)) - sim_ii ), sim = (v̂·û^T)/T
// Logits bounded by 1/T=14.29 -> no max subtraction needed.
//
// R2..R9: all LDS-staged 2-phase variants plateau 224-280us (DS pipe +
//     barrier serialization). R8: direct frag loads from ROW-MAJOR global
//     -> uncoalesced, FETCH 528MB, dead.
// R10: FRAGMENT-MAJOR layout (K1 packs V',U' in exact MFMA fragment order;
//     K2 is LDS-free, barrier-free). Correct (absmax 0), FETCH 37MB (L2
//     absorbed the B re-reads) -- but 345us, MfmaUtil 15.8%:
//     (1) A-frags SPILLED (VGPR=88 < needed ~150; WRITE 33.8MB = scratch),
//     (2) B pipeline depth 1: 40cyc MFMA vs ~250cyc L2 latency at only
//         8 waves/CU -> 40/250 = 16% = measured MfmaUtil.
// R11: same skeleton, latency engineering:
//     (a) __launch_bounds__(256,2): 256-VGPR budget, A(64)+Bring(64)+
//         acc(32) resident, ~190 total, 2 waves/SIMD by design.
//     (b) depth-4 B ring bb[4][4], bank=ks&3 (compile-time in unrolled
//         loop): consume bank, refill it for step ks+4; sched_barrier(0)
//         after each prefetch cluster pins the interleave (R5 lesson).
//         ks 4..7 prefetch next jt's ks0..3 -> per-jt exp2/colsum epilogue
//         hides them. Last jt wraps to jt0 (harmless valid reloads).
//     Design roofline: B stream 4GB through L2 at 34.5TB/s ~ 116us.
//     Gates: VGPR ~180-220 & WRITE ~17MB (spill gone), MfmaUtil >= 45%.

#define D_DIM 256

constexpr float INV_T = 1.0f / 0.07f;
constexpr float EXP2_SCALE = 1.44269504088896340736f / 0.07f;  // log2(e)/T

typedef __bf16 bf16x8 __attribute__((ext_vector_type(8)));
typedef float f32x4 __attribute__((ext_vector_type(4)));

// ---------------------------------------------------------------------------
// Kernel 1: L2-normalize fp32 -> bf16 in FRAGMENT-MAJOR layout.
// One wave = 2 rows: lane = sub(1)|pos(5); lane handles 8 elems
// [pos*8, +8) of row (blk*8 + wave*2 + sub). Norm-reduce over the
// 32-lane half (xor offsets 1..16 stay within the half).
// Fragment write: row r -> group g=r>>4, slot l15=r&15; chunk pos ->
// ks=pos>>2, quad=pos&3; elem offset (g*8+ks)*512 + (quad*16+l15)*8.
// V' pre-scaled by EXP2_SCALE; diag from unscaled v,u; zeroes row/colsum.
// (R10-verified: absmax 0.)
// ---------------------------------------------------------------------------
__global__ __launch_bounds__(256) void normalize_kernel(
    const float* __restrict__ img, const float* __restrict__ txt,
    __hip_bfloat16* __restrict__ Vf, __hip_bfloat16* __restrict__ Uf,
    float* __restrict__ diagarr, float* __restrict__ rowsum,
    float* __restrict__ colsum) {
  const int wave = threadIdx.x >> 6;
  const int lane = threadIdx.x & 63;
  const int sub = lane >> 5;   // 0/1: which of the wave's two rows
  const int pos = lane & 31;   // 8-elem chunk index within the row
  const int row = blockIdx.x * 8 + wave * 2 + sub;
  const size_t base = (size_t)row * D_DIM + pos * 8;

  const float4 i0 = *reinterpret_cast<const float4*>(&img[base]);
  const float4 i1 = *reinterpret_cast<const float4*>(&img[base + 4]);
  const float4 t0 = *reinterpret_cast<const float4*>(&txt[base]);
  const float4 t1 = *reinterpret_cast<const float4*>(&txt[base + 4]);

  float a = i0.x * i0.x + i0.y * i0.y + i0.z * i0.z + i0.w * i0.w +
            i1.x * i1.x + i1.y * i1.y + i1.z * i1.z + i1.w * i1.w;
  float b = t0.x * t0.x + t0.y * t0.y + t0.z * t0.z + t0.w * t0.w +
            t1.x * t1.x + t1.y * t1.y + t1.z * t1.z + t1.w * t1.w;
#pragma unroll
  for (int off = 1; off < 32; off <<= 1) {
    a += __shfl_xor(a, off, 64);
    b += __shfl_xor(b, off, 64);
  }
  const float si = 1.0f / fmaxf(sqrtf(a), 1e-8f);
  const float st = 1.0f / fmaxf(sqrtf(b), 1e-8f);

  const float vs = si * EXP2_SCALE;  // V pre-scaled by log2e/T
  __hip_bfloat16 vb8[8] = {
      __float2bfloat16(i0.x * vs), __float2bfloat16(i0.y * vs),
      __float2bfloat16(i0.z * vs), __float2bfloat16(i0.w * vs),
      __float2bfloat16(i1.x * vs), __float2bfloat16(i1.y * vs),
      __float2bfloat16(i1.z * vs), __float2bfloat16(i1.w * vs)};
  __hip_bfloat16 ub8[8] = {
      __float2bfloat16(t0.x * st), __float2bfloat16(t0.y * st),
      __float2bfloat16(t0.z * st), __float2bfloat16(t0.w * st),
      __float2bfloat16(t1.x * st), __float2bfloat16(t1.y * st),
      __float2bfloat16(t1.z * st), __float2bfloat16(t1.w * st)};

  const int g = row >> 4, l15r = row & 15;
  const int ks = pos >> 2, quad = pos & 3;
  const size_t foff = (size_t)(g * 8 + ks) * 512 + (quad * 16 + l15r) * 8;
  *reinterpret_cast<uint4*>(&Vf[foff]) = *reinterpret_cast<uint4*>(vb8);
  *reinterpret_cast<uint4*>(&Uf[foff]) = *reinterpret_cast<uint4*>(ub8);

  // diag v̂_i·û_i (unscaled)
  float d = (i0.x * si) * (t0.x * st) + (i0.y * si) * (t0.y * st) +
            (i0.z * si) * (t0.z * st) + (i0.w * si) * (t0.w * st) +
            (i1.x * si) * (t1.x * st) + (i1.y * si) * (t1.y * st) +
            (i1.z * si) * (t1.z * st) + (i1.w * si) * (t1.w * st);
#pragma unroll
  for (int off = 1; off < 32; off <<= 1) d += __shfl_xor(d, off, 64);
  if (pos == 0) diagarr[row] = d;

  if (threadIdx.x < 8) {
    rowsum[blockIdx.x * 8 + threadIdx.x] = 0.0f;
    colsum[blockIdx.x * 8 + threadIdx.x] = 0.0f;
  }
}

// ---------------------------------------------------------------------------
// Kernel 2: barrier-free, LDS-free streaming MFMA GEMM + online exp2 sums.
// Block = 32 rows x all N cols; 4 waves partition cols (w*64 per jt).
// A-frags (64 VGPR) resident for the whole kernel. B: depth-4 ring
// bb[4][4]; step ks consumes bank ks&3 then refills it for step ks+4
// (ks>=4 reaches into jt+1); sched_barrier(0) pins each prefetch cluster.
// acc layout (verified): row = mi*16 + quad*4 + r, col = ni*16 + l15.
// ---------------------------------------------------------------------------
__global__ __launch_bounds__(256, 2) void gemm_lse_kernel(
    const __hip_bfloat16* __restrict__ Vf, const __hip_bfloat16* __restrict__ Uf,
    float* __restrict__ rowsum, float* __restrict__ colsum, int n) {
  const int tid = threadIdx.x;
  const int lane = tid & 63;
  const int w = tid >> 6;
  const int quad = lane >> 4;
  const int l15 = lane & 15;
  const int b = blockIdx.x;
  const int njt = n >> 8;  // j-tiles of 256 cols

  // A fragments for rows [b*32, +32): groups 2b, 2b+1 -- all K, once.
  bf16x8 a[2][8];
#pragma unroll
  for (int mi = 0; mi < 2; ++mi)
#pragma unroll
    for (int ks = 0; ks < 8; ++ks)
      a[mi][ks] = *reinterpret_cast<const bf16x8*>(
          Vf + (size_t)((2 * b + mi) * 8 + ks) * 512 + lane * 8);

  float rs[2][4] = {};  // rowsum partials (all jt)

  // B base for this wave: frag(jt, ni, ks) at jt*65536 + (ni*8+ks)*512.
  const __hip_bfloat16* Ub = Uf + (size_t)(w * 4) * 8 * 512 + lane * 8;

  // Depth-4 ring: bank = ks&3. Prologue: jt0 ks0..3.
  bf16x8 bb[4][4];
#pragma unroll
  for (int ks = 0; ks < 4; ++ks)
#pragma unroll
    for (int ni = 0; ni < 4; ++ni)
      bb[ks][ni] = *reinterpret_cast<const bf16x8*>(
          Ub + (size_t)(ni * 8 + ks) * 512);

  for (int jt = 0; jt < njt; ++jt) {
    const size_t jb = (size_t)jt * (16 * 8 * 512);
    const size_t jbn = (jt < njt - 1) ? jb + 16 * 8 * 512 : 0;  // wrap: jt0
    f32x4 acc[2][4] = {};

#pragma unroll
    for (int ks = 0; ks < 8; ++ks) {
      // consume bank ks&3 (compiler inserts the vmcnt wait for these regs)
#pragma unroll
      for (int mi = 0; mi < 2; ++mi)
#pragma unroll
        for (int ni = 0; ni < 4; ++ni)
          acc[mi][ni] = __builtin_amdgcn_mfma_f32_16x16x32_bf16(
              a[mi][ks], bb[ks & 3][ni], acc[mi][ni], 0, 0, 0);
      // refill the just-consumed bank for step ks+4 (ks>=4 -> next jt);
      // WAR on bb keeps these after the MFMAs, sched_barrier stops sinking.
      {
        const size_t pjb = (ks < 4) ? jb : jbn;
        const int pks = (ks < 4) ? ks + 4 : ks - 4;
#pragma unroll
        for (int ni = 0; ni < 4; ++ni)
          bb[ks & 3][ni] = *reinterpret_cast<const bf16x8*>(
              Ub + pjb + (size_t)(ni * 8 + pks) * 512);
        __builtin_amdgcn_sched_barrier(0);
      }
    }

    // per-jt epilogue: exp2, rowsum regs, colsum atomics (cols wave-excl.)
    // -- also the latency cover for the next jt's ks0..3 prefetches.
    float cs0 = 0.f, cs1 = 0.f, cs2 = 0.f, cs3 = 0.f;
#pragma unroll
    for (int mi = 0; mi < 2; ++mi)
#pragma unroll
      for (int r = 0; r < 4; ++r) {
        const float e0 = __builtin_amdgcn_exp2f(acc[mi][0][r]);
        const float e1 = __builtin_amdgcn_exp2f(acc[mi][1][r]);
        const float e2 = __builtin_amdgcn_exp2f(acc[mi][2][r]);
        const float e3 = __builtin_amdgcn_exp2f(acc[mi][3][r]);
        rs[mi][r] += e0 + e1 + e2 + e3;
        cs0 += e0; cs1 += e1; cs2 += e2; cs3 += e3;
      }
    float csa[4] = {cs0, cs1, cs2, cs3};
#pragma unroll
    for (int ni = 0; ni < 4; ++ni) {
      float c = csa[ni];
      c += __shfl_xor(c, 16, 64);
      c += __shfl_xor(c, 32, 64);
      if (lane < 16)
        atomicAdd(&colsum[jt * 256 + w * 64 + ni * 16 + l15], c);
    }
  }

  // final rowsum: reduce over the 16 l15 lanes; 4 waves meet via atomics.
#pragma unroll
  for (int mi = 0; mi < 2; ++mi)
#pragma unroll
    for (int r = 0; r < 4; ++r) {
      float v = rs[mi][r];
      v += __shfl_xor(v, 1, 64);
      v += __shfl_xor(v, 2, 64);
      v += __shfl_xor(v, 4, 64);
      v += __shfl_xor(v, 8, 64);
      if (l15 == 0)
        atomicAdd(&rowsum[b * 32 + mi * 16 + quad * 4 + r], v);
    }
}

// ---------------------------------------------------------------------------
// Kernel 3: finalize — mean(log(rowsum)), mean(log(colsum)), mean(diag).
// ---------------------------------------------------------------------------
__global__ __launch_bounds__(1024) void finalize_kernel(
    const float* __restrict__ rowsum, const float* __restrict__ colsum,
    const float* __restrict__ diagarr, float* __restrict__ out, int n) {
  __shared__ float sh[48];
  float sr = 0.0f, sc = 0.0f, sd = 0.0f;
  for (int i = threadIdx.x; i < n; i += 1024) {
    sr += __logf(rowsum[i]);
    sc += __logf(colsum[i]);
    sd += diagarr[i];
  }
#pragma unroll
  for (int off = 1; off < 64; off <<= 1) {
    sr += __shfl_xor(sr, off, 64);
    sc += __shfl_xor(sc, off, 64);
    sd += __shfl_xor(sd, off, 64);
  }
  const int w = threadIdx.x >> 6, lane = threadIdx.x & 63;
  if (lane == 0) { sh[w] = sr; sh[16 + w] = sc; sh[32 + w] = sd; }
  __syncthreads();
  if (threadIdx.x == 0) {
    float tr = 0.0f, tc = 0.0f, td = 0.0f;
#pragma unroll
    for (int i = 0; i < 16; ++i) {
      tr += sh[i]; tc += sh[16 + i]; td += sh[32 + i];
    }
    const float invN = 1.0f / (float)n;
    const float dm = td * INV_T * invN;   // mean diag logit
    const float lvu = tr * invN - dm;
    const float luv = tc * invN - dm;
    out[0] = 0.5f * lvu + 0.5f * luv;  // WEIGHT = 0.5
    out[1] = lvu;
    out[2] = luv;
  }
}

extern "C" void kernel_launch(void* const* d_in, const int* in_sizes, int n_in,
                              void* d_out, int out_size, void* d_ws, size_t ws_size,
                              hipStream_t stream) {
  const float* img = (const float*)d_in[0];
  const float* txt = (const float*)d_in[1];
  float* out = (float*)d_out;
  const int N = in_sizes[0] / D_DIM;  // 16384

  char* ws = (char*)d_ws;
  __hip_bfloat16* Vf = (__hip_bfloat16*)ws;                             // 8MB
  __hip_bfloat16* Uf = (__hip_bfloat16*)(ws + (size_t)N * D_DIM * 2);   // 8MB
  float* rowsum = (float*)(ws + (size_t)N * D_DIM * 4);
  float* colsum = rowsum + N;
  float* diagarr = colsum + N;

  // rowsum/colsum zeroed inside normalize_kernel (ws poisoned pre-launch)
  normalize_kernel<<<N / 8, 256, 0, stream>>>(img, txt, Vf, Uf, diagarr,
                                              rowsum, colsum);

  gemm_lse_kernel<<<N / 32, 256, 0, stream>>>(Vf, Uf, rowsum, colsum, N);

  finalize_kernel<<<1, 1024, 0, stream>>>(rowsum, colsum, diagarr, out, N);
}

// Round 10
// 223.064 us; speedup vs baseline: 1.9067x; 1.1742x over previous
//
#include <hip/hip_runtime.h>
#include <hip/hip_bf16.h>

// NT-Xent (CLIP) loss, N=16384 D=256 fp32 in, 3 fp32 out.
// loss_vu = mean_i( log(sum_j exp(sim_ij)) - sim_ii ), sim = (v̂·û^T)/T
// Logits bounded by 1/T=14.29 -> no max subtraction needed.
//
// R2..R9: LDS-staged 2-phase variants plateau 224-280us.
// R10: FRAGMENT-MAJOR layout (K1 packs V',U' in MFMA fragment order; K2
//     LDS-free barrier-free). 345us -- B pipeline depth 1.
// R11: depth-4 B ring + 256-VGPR budget: 196us, MfmaUtil 31%. Bookkeeping
//     fixes: WRITE 33.8MB = colsum atomics (NOT spill; R10==R11 bytes);
//     MFMA cost is per-SIMD (19.4cyc) -> 34% busy == measured ✓.
//     Binding resource now: B-stream = 512 blocks x 8MB = 4GB through
//     L2/L3 at ~20TB/s effective = ~160us of the 196.
// R12: double arithmetic intensity per B-byte: 64 ROWS/BLOCK.
//     256 blocks x 512thr (8 waves, 1 block/CU, 2 waves/SIMD). Wave owns
//     all 4 row-groups (A=128 VGPR, read once) x 64-col slice of a
//     512-col j-tile (njt=32). B traffic halves to 2GB. B ring depth 2
//     (1-step slack ~300-600cyc covers L2). Budget: A128+acc64+bb32+rs16
//     ~ 240/256. Gates: WRITE ~17MB (rise>25MB = real spill -> abort),
//     MfmaUtil >= 45%, K2 <= 140us.

#define D_DIM 256

constexpr float INV_T = 1.0f / 0.07f;
constexpr float EXP2_SCALE = 1.44269504088896340736f / 0.07f;  // log2(e)/T

typedef __bf16 bf16x8 __attribute__((ext_vector_type(8)));
typedef float f32x4 __attribute__((ext_vector_type(4)));

// ---------------------------------------------------------------------------
// Kernel 1: L2-normalize fp32 -> bf16 in FRAGMENT-MAJOR layout.
// One wave = 2 rows: lane = sub(1)|pos(5); lane handles 8 elems
// [pos*8, +8) of row (blk*8 + wave*2 + sub). Norm-reduce over the
// 32-lane half (xor offsets 1..16 stay within the half).
// Fragment write: row r -> group g=r>>4, slot l15=r&15; chunk pos ->
// ks=pos>>2, quad=pos&3; elem offset (g*8+ks)*512 + (quad*16+l15)*8.
// V' pre-scaled by EXP2_SCALE; diag from unscaled v,u; zeroes row/colsum.
// (R10/R11-verified: absmax 0.)
// ---------------------------------------------------------------------------
__global__ __launch_bounds__(256) void normalize_kernel(
    const float* __restrict__ img, const float* __restrict__ txt,
    __hip_bfloat16* __restrict__ Vf, __hip_bfloat16* __restrict__ Uf,
    float* __restrict__ diagarr, float* __restrict__ rowsum,
    float* __restrict__ colsum) {
  const int wave = threadIdx.x >> 6;
  const int lane = threadIdx.x & 63;
  const int sub = lane >> 5;   // 0/1: which of the wave's two rows
  const int pos = lane & 31;   // 8-elem chunk index within the row
  const int row = blockIdx.x * 8 + wave * 2 + sub;
  const size_t base = (size_t)row * D_DIM + pos * 8;

  const float4 i0 = *reinterpret_cast<const float4*>(&img[base]);
  const float4 i1 = *reinterpret_cast<const float4*>(&img[base + 4]);
  const float4 t0 = *reinterpret_cast<const float4*>(&txt[base]);
  const float4 t1 = *reinterpret_cast<const float4*>(&txt[base + 4]);

  float a = i0.x * i0.x + i0.y * i0.y + i0.z * i0.z + i0.w * i0.w +
            i1.x * i1.x + i1.y * i1.y + i1.z * i1.z + i1.w * i1.w;
  float b = t0.x * t0.x + t0.y * t0.y + t0.z * t0.z + t0.w * t0.w +
            t1.x * t1.x + t1.y * t1.y + t1.z * t1.z + t1.w * t1.w;
#pragma unroll
  for (int off = 1; off < 32; off <<= 1) {
    a += __shfl_xor(a, off, 64);
    b += __shfl_xor(b, off, 64);
  }
  const float si = 1.0f / fmaxf(sqrtf(a), 1e-8f);
  const float st = 1.0f / fmaxf(sqrtf(b), 1e-8f);

  const float vs = si * EXP2_SCALE;  // V pre-scaled by log2e/T
  __hip_bfloat16 vb8[8] = {
      __float2bfloat16(i0.x * vs), __float2bfloat16(i0.y * vs),
      __float2bfloat16(i0.z * vs), __float2bfloat16(i0.w * vs),
      __float2bfloat16(i1.x * vs), __float2bfloat16(i1.y * vs),
      __float2bfloat16(i1.z * vs), __float2bfloat16(i1.w * vs)};
  __hip_bfloat16 ub8[8] = {
      __float2bfloat16(t0.x * st), __float2bfloat16(t0.y * st),
      __float2bfloat16(t0.z * st), __float2bfloat16(t0.w * st),
      __float2bfloat16(t1.x * st), __float2bfloat16(t1.y * st),
      __float2bfloat16(t1.z * st), __float2bfloat16(t1.w * st)};

  const int g = row >> 4, l15r = row & 15;
  const int ks = pos >> 2, quad = pos & 3;
  const size_t foff = (size_t)(g * 8 + ks) * 512 + (quad * 16 + l15r) * 8;
  *reinterpret_cast<uint4*>(&Vf[foff]) = *reinterpret_cast<uint4*>(vb8);
  *reinterpret_cast<uint4*>(&Uf[foff]) = *reinterpret_cast<uint4*>(ub8);

  // diag v̂_i·û_i (unscaled)
  float d = (i0.x * si) * (t0.x * st) + (i0.y * si) * (t0.y * st) +
            (i0.z * si) * (t0.z * st) + (i0.w * si) * (t0.w * st) +
            (i1.x * si) * (t1.x * st) + (i1.y * si) * (t1.y * st) +
            (i1.z * si) * (t1.z * st) + (i1.w * si) * (t1.w * st);
#pragma unroll
  for (int off = 1; off < 32; off <<= 1) d += __shfl_xor(d, off, 64);
  if (pos == 0) diagarr[row] = d;

  if (threadIdx.x < 8) {
    rowsum[blockIdx.x * 8 + threadIdx.x] = 0.0f;
    colsum[blockIdx.x * 8 + threadIdx.x] = 0.0f;
  }
}

// ---------------------------------------------------------------------------
// Kernel 2: barrier-free, LDS-free streaming MFMA GEMM + online exp2 sums.
// Block = 64 rows (groups 4b..4b+3) x all N cols; 8 waves; wave w covers
// cols [jt*512 + w*64, +64) of each 512-col j-tile (njt = 32).
// A-frags a[4][8] (128 VGPR) resident for the whole kernel.
// B: depth-2 ring bb[2][4], bank = ks&1; at step ks issue load(ks+1) into
// bank (ks+1)&1 (consumed at ks-1, free), then MFMA-consume bank ks&1;
// ks=7 prefetches next jt's ks0, covered by the per-jt exp2/colsum
// epilogue. sched_barrier(0) pins each prefetch cluster (R5 lesson).
// acc layout (verified): row = mi*16 + quad*4 + r, col = ni*16 + l15.
// ---------------------------------------------------------------------------
__global__ __launch_bounds__(512, 2) void gemm_lse_kernel(
    const __hip_bfloat16* __restrict__ Vf, const __hip_bfloat16* __restrict__ Uf,
    float* __restrict__ rowsum, float* __restrict__ colsum, int n) {
  const int tid = threadIdx.x;
  const int lane = tid & 63;
  const int w = tid >> 6;        // 0..7
  const int quad = lane >> 4;
  const int l15 = lane & 15;
  const int b = blockIdx.x;
  const int njt = n >> 9;        // j-tiles of 512 cols

  // A fragments for rows [b*64, +64): groups 4b..4b+3, all K, once.
  bf16x8 a[4][8];
#pragma unroll
  for (int mi = 0; mi < 4; ++mi)
#pragma unroll
    for (int ks = 0; ks < 8; ++ks)
      a[mi][ks] = *reinterpret_cast<const bf16x8*>(
          Vf + (size_t)((4 * b + mi) * 8 + ks) * 512 + lane * 8);

  float rs[4][4] = {};  // rowsum partials (mi, r), all jt

  // B base for this wave: col group = jt*32 + w*4 + ni; frag at
  // (group*8 + ks)*512 + lane*8.
  const __hip_bfloat16* Ub = Uf + (size_t)(w * 4) * 8 * 512 + lane * 8;

  // Depth-2 ring. Prologue: jt0 ks0 -> bank 0.
  bf16x8 bb[2][4];
#pragma unroll
  for (int ni = 0; ni < 4; ++ni)
    bb[0][ni] = *reinterpret_cast<const bf16x8*>(Ub + (size_t)(ni * 8) * 512);

  for (int jt = 0; jt < njt; ++jt) {
    const size_t jb = (size_t)jt * (32 * 8 * 512);
    const size_t jbn = (jt < njt - 1) ? jb + 32 * 8 * 512 : 0;  // wrap: jt0
    f32x4 acc[4][4] = {};

#pragma unroll
    for (int ks = 0; ks < 8; ++ks) {
      // issue load for step ks+1 into the other bank (free since ks-1)
      {
        const size_t pjb = (ks < 7) ? jb : jbn;
        const int pks = (ks < 7) ? ks + 1 : 0;
#pragma unroll
        for (int ni = 0; ni < 4; ++ni)
          bb[(ks + 1) & 1][ni] = *reinterpret_cast<const bf16x8*>(
              Ub + pjb + (size_t)(ni * 8 + pks) * 512);
        __builtin_amdgcn_sched_barrier(0);
      }
      // consume bank ks&1 (waitcnt inserted for its step-(ks-1) loads)
#pragma unroll
      for (int mi = 0; mi < 4; ++mi)
#pragma unroll
        for (int ni = 0; ni < 4; ++ni)
          acc[mi][ni] = __builtin_amdgcn_mfma_f32_16x16x32_bf16(
              a[mi][ks], bb[ks & 1][ni], acc[mi][ni], 0, 0, 0);
    }

    // per-jt epilogue: exp2, rowsum regs, colsum atomics (cols wave-excl.)
    // -- also the latency cover for the next jt's ks0 prefetch.
    float cs0 = 0.f, cs1 = 0.f, cs2 = 0.f, cs3 = 0.f;
#pragma unroll
    for (int mi = 0; mi < 4; ++mi)
#pragma unroll
      for (int r = 0; r < 4; ++r) {
        const float e0 = __builtin_amdgcn_exp2f(acc[mi][0][r]);
        const float e1 = __builtin_amdgcn_exp2f(acc[mi][1][r]);
        const float e2 = __builtin_amdgcn_exp2f(acc[mi][2][r]);
        const float e3 = __builtin_amdgcn_exp2f(acc[mi][3][r]);
        rs[mi][r] += e0 + e1 + e2 + e3;
        cs0 += e0; cs1 += e1; cs2 += e2; cs3 += e3;
      }
    float csa[4] = {cs0, cs1, cs2, cs3};
#pragma unroll
    for (int ni = 0; ni < 4; ++ni) {
      float c = csa[ni];
      c += __shfl_xor(c, 16, 64);
      c += __shfl_xor(c, 32, 64);
      if (lane < 16)
        atomicAdd(&colsum[jt * 512 + w * 64 + ni * 16 + l15], c);
    }
  }

  // final rowsum: reduce over the 16 l15 lanes; 8 waves meet via atomics.
#pragma unroll
  for (int mi = 0; mi < 4; ++mi)
#pragma unroll
    for (int r = 0; r < 4; ++r) {
      float v = rs[mi][r];
      v += __shfl_xor(v, 1, 64);
      v += __shfl_xor(v, 2, 64);
      v += __shfl_xor(v, 4, 64);
      v += __shfl_xor(v, 8, 64);
      if (l15 == 0)
        atomicAdd(&rowsum[b * 64 + mi * 16 + quad * 4 + r], v);
    }
}

// ---------------------------------------------------------------------------
// Kernel 3: finalize — mean(log(rowsum)), mean(log(colsum)), mean(diag).
// ---------------------------------------------------------------------------
__global__ __launch_bounds__(1024) void finalize_kernel(
    const float* __restrict__ rowsum, const float* __restrict__ colsum,
    const float* __restrict__ diagarr, float* __restrict__ out, int n) {
  __shared__ float sh[48];
  float sr = 0.0f, sc = 0.0f, sd = 0.0f;
  for (int i = threadIdx.x; i < n; i += 1024) {
    sr += __logf(rowsum[i]);
    sc += __logf(colsum[i]);
    sd += diagarr[i];
  }
#pragma unroll
  for (int off = 1; off < 64; off <<= 1) {
    sr += __shfl_xor(sr, off, 64);
    sc += __shfl_xor(sc, off, 64);
    sd += __shfl_xor(sd, off, 64);
  }
  const int w = threadIdx.x >> 6, lane = threadIdx.x & 63;
  if (lane == 0) { sh[w] = sr; sh[16 + w] = sc; sh[32 + w] = sd; }
  __syncthreads();
  if (threadIdx.x == 0) {
    float tr = 0.0f, tc = 0.0f, td = 0.0f;
#pragma unroll
    for (int i = 0; i < 16; ++i) {
      tr += sh[i]; tc += sh[16 + i]; td += sh[32 + i];
    }
    const float invN = 1.0f / (float)n;
    const float dm = td * INV_T * invN;   // mean diag logit
    const float lvu = tr * invN - dm;
    const float luv = tc * invN - dm;
    out[0] = 0.5f * lvu + 0.5f * luv;  // WEIGHT = 0.5
    out[1] = lvu;
    out[2] = luv;
  }
}

extern "C" void kernel_launch(void* const* d_in, const int* in_sizes, int n_in,
                              void* d_out, int out_size, void* d_ws, size_t ws_size,
                              hipStream_t stream) {
  const float* img = (const float*)d_in[0];
  const float* txt = (const float*)d_in[1];
  float* out = (float*)d_out;
  const int N = in_sizes[0] / D_DIM;  // 16384

  char* ws = (char*)d_ws;
  __hip_bfloat16* Vf = (__hip_bfloat16*)ws;                             // 8MB
  __hip_bfloat16* Uf = (__hip_bfloat16*)(ws + (size_t)N * D_DIM * 2);   // 8MB
  float* rowsum = (float*)(ws + (size_t)N * D_DIM * 4);
  float* colsum = rowsum + N;
  float* diagarr = colsum + N;

  // rowsum/colsum zeroed inside normalize_kernel (ws poisoned pre-launch)
  normalize_kernel<<<N / 8, 256, 0, stream>>>(img, txt, Vf, Uf, diagarr,
                                              rowsum, colsum);

  gemm_lse_kernel<<<N / 64, 512, 0, stream>>>(Vf, Uf, rowsum, colsum, N);

  finalize_kernel<<<1, 1024, 0, stream>>>(rowsum, colsum, diagarr, out, N);
}